// Round 4
// baseline (203.660 us; speedup 1.0000x reference)
//
#include <hip/hip_runtime.h>
#include <hip/hip_bf16.h>
#include <math.h>

#define NH 8
#define DMv 512
#define BSv 8
#define NQv 100
#define NKv 100

typedef __attribute__((ext_vector_type(8))) short short8;
typedef __attribute__((ext_vector_type(4))) float f32x4;

__device__ __forceinline__ unsigned short bf16u(float f) {
    __hip_bfloat16 h = __float2bfloat16(f);
    return *(unsigned short*)&h;
}
__device__ __forceinline__ float ubf16f(unsigned short u) {
    __hip_bfloat16 h = *(__hip_bfloat16*)&u;
    return __bfloat162float(h);
}
__device__ __forceinline__ unsigned int pkbf(float lo, float hi) {
    return ((unsigned int)bf16u(hi) << 16) | (unsigned int)bf16u(lo);
}

// ---------------- Kernel 0: weight transpose + bf16 convert ----------------
__global__ __launch_bounds__(256) void wt_kernel(
    const float* __restrict__ W_q1, const float* __restrict__ W_q2,
    const float* __restrict__ W_k,  const float* __restrict__ W_v,
    const float* __restrict__ W_o,  unsigned short* __restrict__ wt)
{
    __shared__ float tile[64][68];
    const int z = blockIdx.z;
    const float* W = (z == 0) ? W_q1 : (z == 1) ? W_q2 : (z == 2) ? W_k : (z == 3) ? W_v : W_o;
    unsigned short* out = wt + (size_t)z * 512 * 512;
    const int k0 = blockIdx.x * 64, n0 = blockIdx.y * 64;
    const int t = threadIdx.x;
    const int r = t >> 2, c = t & 3;
#pragma unroll
    for (int i = 0; i < 4; i++) {
        float4 v = *(const float4*)&W[(size_t)(k0 + r) * 512 + n0 + c * 16 + i * 4];
        *(float4*)&tile[r][c * 16 + i * 4] = v;
    }
    __syncthreads();
#pragma unroll
    for (int jj = 0; jj < 4; jj++) {
        const int kb = c * 16 + jj * 4;
        ushort4 u;
        u.x = bf16u(tile[kb + 0][r]); u.y = bf16u(tile[kb + 1][r]);
        u.z = bf16u(tile[kb + 2][r]); u.w = bf16u(tile[kb + 3][r]);
        *(ushort4*)&out[(size_t)(n0 + r) * 512 + k0 + kb] = u;
    }
}

// ---------------- Kernel A: MFMA proj GEMM + bias + ELU + GroupNorm ----------------
__global__ __launch_bounds__(256) void proj_kernel(
    const float* __restrict__ xq, const float* __restrict__ xk, const float* __restrict__ xv,
    const unsigned short* __restrict__ wt,
    const float* __restrict__ bq1, const float* __restrict__ gq1w, const float* __restrict__ gq1b,
    const float* __restrict__ bq2, const float* __restrict__ gq2w, const float* __restrict__ gq2b,
    const float* __restrict__ bk,  const float* __restrict__ gkw,  const float* __restrict__ gkb,
    const float* __restrict__ bv,  const float* __restrict__ gvw,  const float* __restrict__ gvb,
    float* __restrict__ q1o, float* __restrict__ q2o, float* __restrict__ ko, float* __restrict__ vo)
{
    __shared__ char A_s[64 * 144];
    __shared__ char B_s[64 * 144];
    __shared__ float Y_s[64][68];

    const int p = blockIdx.z;
    const float *x, *bb, *gw, *gb;
    float* o;
    if (p == 0)      { x = xq; bb = bq1; gw = gq1w; gb = gq1b; o = q1o; }
    else if (p == 1) { x = xq; bb = bq2; gw = gq2w; gb = gq2b; o = q2o; }
    else if (p == 2) { x = xk; bb = bk;  gw = gkw;  gb = gkb;  o = ko;  }
    else             { x = xv; bb = bv;  gw = gvw;  gb = gvb;  o = vo;  }
    const unsigned short* WT = wt + (size_t)p * 512 * 512;

    const int t = threadIdx.x;
    const int r0 = blockIdx.x * 64;
    const int ct = blockIdx.y;

    const int lane = t & 63, wave = t >> 6;
    const int wr = wave >> 1, wc = wave & 1;
    const int lr = lane & 15, lq = lane >> 4;
    const int srow = t >> 2, sc = t & 3;

    f32x4 acc[2][2];
#pragma unroll
    for (int i = 0; i < 2; i++)
#pragma unroll
        for (int j = 0; j < 2; j++) acc[i][j] = (f32x4){0.f, 0.f, 0.f, 0.f};

    const int arow = (r0 + srow < 800) ? (r0 + srow) : 799;

    for (int kk = 0; kk < 8; kk++) {
        const int k0 = kk * 64;
#pragma unroll
        for (int uu = 0; uu < 2; uu++) {
            const int u = sc * 2 + uu;
            float4 f0 = *(const float4*)&x[(size_t)arow * 512 + k0 + u * 8];
            float4 f1 = *(const float4*)&x[(size_t)arow * 512 + k0 + u * 8 + 4];
            uint4 w;
            w.x = pkbf(f0.x, f0.y); w.y = pkbf(f0.z, f0.w);
            w.z = pkbf(f1.x, f1.y); w.w = pkbf(f1.z, f1.w);
            *(uint4*)(A_s + srow * 144 + u * 16) = w;
        }
#pragma unroll
        for (int uu = 0; uu < 2; uu++) {
            const int u = sc * 2 + uu;
            uint4 w = *(const uint4*)((const char*)(WT + (size_t)(ct * 64 + srow) * 512 + k0) + u * 16);
            *(uint4*)(B_s + srow * 144 + u * 16) = w;
        }
        __syncthreads();
#pragma unroll
        for (int ks = 0; ks < 2; ks++) {
            short8 a0 = *(const short8*)(A_s + (wr * 32 + lr) * 144 + (ks * 4 + lq) * 16);
            short8 a1 = *(const short8*)(A_s + (wr * 32 + 16 + lr) * 144 + (ks * 4 + lq) * 16);
            short8 b0 = *(const short8*)(B_s + (wc * 32 + lr) * 144 + (ks * 4 + lq) * 16);
            short8 b1 = *(const short8*)(B_s + (wc * 32 + 16 + lr) * 144 + (ks * 4 + lq) * 16);
            acc[0][0] = __builtin_amdgcn_mfma_f32_16x16x32_bf16(a0, b0, acc[0][0], 0, 0, 0);
            acc[0][1] = __builtin_amdgcn_mfma_f32_16x16x32_bf16(a0, b1, acc[0][1], 0, 0, 0);
            acc[1][0] = __builtin_amdgcn_mfma_f32_16x16x32_bf16(a1, b0, acc[1][0], 0, 0, 0);
            acc[1][1] = __builtin_amdgcn_mfma_f32_16x16x32_bf16(a1, b1, acc[1][1], 0, 0, 0);
        }
        __syncthreads();
    }

#pragma unroll
    for (int nt = 0; nt < 2; nt++) {
        const int colL = wc * 32 + nt * 16 + lr;
        const float bias = bb[ct * 64 + colL];
#pragma unroll
        for (int mt = 0; mt < 2; mt++) {
#pragma unroll
            for (int r = 0; r < 4; r++) {
                const int row = wr * 32 + mt * 16 + lq * 4 + r;
                float y = acc[mt][nt][r] + bias;
                y = (y > 0.f) ? y : expm1f(y);
                Y_s[row][colL] = y;
            }
        }
    }
    __syncthreads();

    {
        const int row = t >> 2, c = t & 3;
        float v[16];
        float s = 0.f, ss = 0.f;
#pragma unroll
        for (int i = 0; i < 16; i++) {
            v[i] = Y_s[row][c * 16 + i];
            s += v[i]; ss += v[i] * v[i];
        }
        s += __shfl_xor(s, 1); ss += __shfl_xor(ss, 1);
        s += __shfl_xor(s, 2); ss += __shfl_xor(ss, 2);
        const float mu = s * (1.f / 64.f);
        const float var = ss * (1.f / 64.f) - mu * mu;
        const float rs = 1.0f / sqrtf(var + 1e-5f);
        const int rowg = r0 + row;
        if (rowg < 800) {
            const int b = rowg / 100, sq = rowg % 100;
            const size_t base = (((size_t)(b * NH + ct) * NQv) + sq) * 64 + c * 16;
            const int j0 = ct * 64 + c * 16;
#pragma unroll
            for (int i4 = 0; i4 < 4; i4++) {
                float4 gwv = *(const float4*)&gw[j0 + i4 * 4];
                float4 gbv = *(const float4*)&gb[j0 + i4 * 4];
                float4 ov;
                ov.x = (v[i4 * 4 + 0] - mu) * rs * gwv.x + gbv.x;
                ov.y = (v[i4 * 4 + 1] - mu) * rs * gwv.y + gbv.y;
                ov.z = (v[i4 * 4 + 2] - mu) * rs * gwv.z + gbv.z;
                ov.w = (v[i4 * 4 + 3] - mu) * rs * gwv.w + gbv.w;
                *(float4*)&o[base + i4 * 4] = ov;
            }
        }
    }
}

// ---------------- Kernel B v3: 2-q per iteration, LDS < 64KB, V/Wc in registers ----------------
__global__ __launch_bounds__(512, 4) void attn_kernel(
    const float* __restrict__ q1g, const float* __restrict__ q2g,
    const float* __restrict__ kg, const float* __restrict__ vg,
    const float* __restrict__ Wm, const float* __restrict__ bm,
    const float* __restrict__ Ws, const float* __restrict__ bs_,
    const float* __restrict__ Wc, const float* __restrict__ bc,
    float* __restrict__ attn_v)
{
    __shared__ unsigned short Wm_s[8192];   // [128 m][64 d] bf16, XOR-swizzled
    __shared__ unsigned short K_s[8192];    // [128 k][64 d] bf16, XOR-swizzled
    __shared__ float q1_s[2][2][64];        // [pair parity][qsel][d]
    __shared__ float q2_s[2][2][64];
    __shared__ float lgp[2][128];           // softmax probs per qsel
    __shared__ float part_l2[2][2][128];    // [qsel][mrow][k]
    __shared__ float part_p3[2][4][132];    // [qsel][ncol][m]
    __shared__ float pool_s[2][128];
    __shared__ float part_sv[2][8][64];
    __shared__ float part_ch[2][8][64];
    __shared__ float2 bmws_s[128];          // (b_m, W_s) packed
    __shared__ float bc_s[64];

    const int t = threadIdx.x;
    const int qt = blockIdx.x;     // 0..7
    const int bh = blockIdx.y;     // 0..63
    const int q0 = (qt < 4) ? qt * 13 : 52 + (qt - 4) * 12;
    const int nq = (qt < 4) ? 13 : 12;

    const float* Kg = kg + (size_t)bh * NKv * 64;
    const float* Vg = vg + (size_t)bh * NKv * 64;

    // ---- prologue staging ----
    for (int i = t; i < 1024; i += 512) {
        const int k = i >> 3, u = i & 7;
        uint4 w;
        if (k < NKv) {
            float4 a = *(const float4*)(Kg + k * 64 + u * 8);
            float4 b = *(const float4*)(Kg + k * 64 + u * 8 + 4);
            w.x = pkbf(a.x, a.y); w.y = pkbf(a.z, a.w);
            w.z = pkbf(b.x, b.y); w.w = pkbf(b.z, b.w);
        } else { w.x = 0u; w.y = 0u; w.z = 0u; w.w = 0u; }
        *(uint4*)((char*)K_s + k * 128 + ((u ^ (k & 7)) * 16)) = w;
    }
    for (int i = t; i < 1024; i += 512) {
        const int u = i >> 7, m = i & 127;
        float f[8];
#pragma unroll
        for (int j = 0; j < 8; j++) f[j] = Wm[(size_t)(u * 8 + j) * 128 + m];
        uint4 w;
        w.x = pkbf(f[0], f[1]); w.y = pkbf(f[2], f[3]);
        w.z = pkbf(f[4], f[5]); w.w = pkbf(f[6], f[7]);
        *(uint4*)((char*)Wm_s + m * 128 + ((u ^ (m & 7)) * 16)) = w;
    }
    if (t < 128) bmws_s[t] = make_float2(bm[t], Ws[t]);
    if (t < 64) bc_s[t] = bc[t];
    if (t >= 128 && t < 384) {   // initial q1/q2 preload: pair 0 -> slot 0
        const int tq = t - 128;
        const int s = tq >> 7, rem = tq & 127, kind = rem >> 6, d = rem & 63;
        const size_t qb = ((size_t)bh * NQv + q0 + s) * 64 + d;
        if (kind == 0) q1_s[0][s][d] = q1g[qb]; else q2_s[0][s][d] = q2g[qb];
    }
    // V / Wc into registers (wave-coalesced; reused every q)
    const int d_pr = t & 63, c_pr = t >> 6;
    unsigned int Vr[7];
#pragma unroll
    for (int i = 0; i < 7; i++) {
        const int k2 = c_pr * 7 + i;
        Vr[i] = (k2 < 50) ? pkbf(Vg[(size_t)(2 * k2) * 64 + d_pr], Vg[(size_t)(2 * k2 + 1) * 64 + d_pr]) : 0u;
    }
    unsigned int Wcr[8];
#pragma unroll
    for (int i = 0; i < 8; i++) {
        const int m2 = c_pr * 8 + i;
        Wcr[i] = pkbf(Wc[(size_t)(2 * m2) * 64 + d_pr], Wc[(size_t)(2 * m2 + 1) * 64 + d_pr]);
    }
    const float bsv = bs_[0];
    __syncthreads();

    const int lane = t & 63, wave = t >> 6;
    const int mrow = wave >> 2, ncol = wave & 3;
    const int lr = lane & 15, lq = lane >> 4;

    short8 afr[4][2];
#pragma unroll
    for (int mti = 0; mti < 4; mti++)
#pragma unroll
        for (int ks = 0; ks < 2; ks++) {
            const int m = mrow * 64 + mti * 16 + lr;
            const int u = ks * 4 + lq;
            afr[mti][ks] = *(const short8*)((const char*)Wm_s + m * 128 + ((u ^ (m & 7)) * 16));
        }
    uint4 Ku[2][2];
#pragma unroll
    for (int nti = 0; nti < 2; nti++)
#pragma unroll
        for (int ks = 0; ks < 2; ks++) {
            const int k = ncol * 32 + nti * 16 + lr;
            const int u = ks * 4 + lq;
            Ku[nti][ks] = *(const uint4*)((const char*)K_s + k * 128 + ((u ^ (k & 7)) * 16));
        }
    const float km0 = (ncol * 32 + lr < 100) ? 1.f : 0.f;
    const float km1 = (ncol * 32 + 16 + lr < 100) ? 1.f : 0.f;

    for (int qi = 0; qi < nq; qi += 2) {
        const int pb = (qi >> 1) & 1;          // pair parity (q_s slot)
        const bool has2 = (qi + 1 < nq);
        const int nS = has2 ? 2 : 1;

        // ---- phase 1: S + logits/pool partials, per q ----
        for (int s = 0; s < nS; s++) {
            f32x4 acc[4][2];
#pragma unroll
            for (int mti = 0; mti < 4; mti++)
#pragma unroll
                for (int nti = 0; nti < 2; nti++) acc[mti][nti] = (f32x4){0.f, 0.f, 0.f, 0.f};

#pragma unroll
            for (int ks = 0; ks < 2; ks++) {
                float q1v[8];
                {
                    float4 x = *(const float4*)((const char*)q1_s[pb][s] + ks * 128 + lq * 32);
                    float4 y = *(const float4*)((const char*)q1_s[pb][s] + ks * 128 + lq * 32 + 16);
                    q1v[0] = x.x; q1v[1] = x.y; q1v[2] = x.z; q1v[3] = x.w;
                    q1v[4] = y.x; q1v[5] = y.y; q1v[6] = y.z; q1v[7] = y.w;
                }
                union { short8 s8; unsigned int u[4]; } bfr0, bfr1;
#pragma unroll
                for (int w = 0; w < 4; w++) {
                    const unsigned int u0 = ((const unsigned int*)&Ku[0][ks])[w];
                    const unsigned int u1 = ((const unsigned int*)&Ku[1][ks])[w];
                    const float k0lo = __uint_as_float(u0 << 16);
                    const float k0hi = __uint_as_float(u0 & 0xffff0000u);
                    const float k1lo = __uint_as_float(u1 << 16);
                    const float k1hi = __uint_as_float(u1 & 0xffff0000u);
                    bfr0.u[w] = pkbf(k0lo * q1v[2 * w], k0hi * q1v[2 * w + 1]);
                    bfr1.u[w] = pkbf(k1lo * q1v[2 * w], k1hi * q1v[2 * w + 1]);
                }
#pragma unroll
                for (int mti = 0; mti < 4; mti++) {
                    acc[mti][0] = __builtin_amdgcn_mfma_f32_16x16x32_bf16(afr[mti][ks], bfr0.s8, acc[mti][0], 0, 0, 0);
                    acc[mti][1] = __builtin_amdgcn_mfma_f32_16x16x32_bf16(afr[mti][ks], bfr1.s8, acc[mti][1], 0, 0, 0);
                }
            }

            float lp0 = 0.f, lp1 = 0.f;
#pragma unroll
            for (int mti = 0; mti < 4; mti++) {
                float ppv[4];
#pragma unroll
                for (int r = 0; r < 4; r++) {
                    const int m = mrow * 64 + mti * 16 + lq * 4 + r;
                    const float2 bw = bmws_s[m];
                    const float v0 = fmaxf(acc[mti][0][r] + bw.x, 0.f);
                    const float v1 = fmaxf(acc[mti][1][r] + bw.x, 0.f);
                    lp0 = fmaf(bw.y, v0, lp0);
                    lp1 = fmaf(bw.y, v1, lp1);
                    float pv = v0 * km0 + v1 * km1;
                    pv += __shfl_xor(pv, 1);
                    pv += __shfl_xor(pv, 2);
                    pv += __shfl_xor(pv, 4);
                    pv += __shfl_xor(pv, 8);
                    ppv[r] = pv;
                }
                if (lr == 0)
                    *(float4*)&part_p3[s][ncol][mrow * 64 + mti * 16 + lq * 4] =
                        make_float4(ppv[0], ppv[1], ppv[2], ppv[3]);
            }
            lp0 += __shfl_xor(lp0, 16); lp0 += __shfl_xor(lp0, 32);
            lp1 += __shfl_xor(lp1, 16); lp1 += __shfl_xor(lp1, 32);
            if (lane < 16) part_l2[s][mrow][ncol * 32 + lane] = lp0;
            else if (lane < 32) part_l2[s][mrow][ncol * 32 + lane] = lp1;
        }
        __syncthreads();

        // ---- phase 2: softmax (waves 0-1) + pool finalize (threads 128-383) ----
        if (t < 128) {
            const int s = t >> 6, l = t & 63;
            if (s < nS) {
                float x0 = part_l2[s][0][l] + part_l2[s][1][l] + bsv;
                float x1 = (l < 36) ? (part_l2[s][0][64 + l] + part_l2[s][1][64 + l] + bsv) : -3.0e38f;
                float mx = fmaxf(x0, x1);
#pragma unroll
                for (int msk = 1; msk <= 32; msk <<= 1) mx = fmaxf(mx, __shfl_xor(mx, msk));
                const float e0 = __expf(x0 - mx);
                const float e1 = (l < 36) ? __expf(x1 - mx) : 0.f;
                float sm = e0 + e1;
#pragma unroll
                for (int msk = 1; msk <= 32; msk <<= 1) sm += __shfl_xor(sm, msk);
                const float inv = 1.f / sm;
                lgp[s][l] = e0 * inv;
                lgp[s][64 + l] = (l < 36) ? e1 * inv : 0.f;
            }
        } else if (t < 384) {
            const int s = (t - 128) >> 7, mm = (t - 128) & 127;
            if (s < nS)
                pool_s[s][mm] = (part_p3[s][0][mm] + part_p3[s][1][mm] +
                                 part_p3[s][2][mm] + part_p3[s][3][mm]) * 0.01f;
        }
        __syncthreads();

        // ---- phase 3: sv / ch partials for both q ----
        {
            const int d = t & 63, c = t >> 6;
            float sv0 = 0.f, sv1 = 0.f;
#pragma unroll
            for (int i = 0; i < 7; i++) {
                const int k2 = c * 7 + i;
                if (k2 < 50) {
                    const unsigned int vp = Vr[i];
                    const float vlo = __uint_as_float(vp << 16);
                    const float vhi = __uint_as_float(vp & 0xffff0000u);
                    const float2 l0 = *(const float2*)&lgp[0][2 * k2];
                    const float2 l1 = *(const float2*)&lgp[1][2 * k2];
                    sv0 = fmaf(l0.x, vlo, sv0); sv0 = fmaf(l0.y, vhi, sv0);
                    sv1 = fmaf(l1.x, vlo, sv1); sv1 = fmaf(l1.y, vhi, sv1);
                }
            }
            part_sv[0][c][d] = sv0; part_sv[1][c][d] = sv1;
            float ch0 = 0.f, ch1 = 0.f;
#pragma unroll
            for (int i = 0; i < 8; i++) {
                const int m2 = c * 8 + i;
                const unsigned int wp = Wcr[i];
                const float wlo = __uint_as_float(wp << 16);
                const float whi = __uint_as_float(wp & 0xffff0000u);
                const float2 p0 = *(const float2*)&pool_s[0][2 * m2];
                const float2 p1 = *(const float2*)&pool_s[1][2 * m2];
                ch0 = fmaf(p0.x, wlo, ch0); ch0 = fmaf(p0.y, whi, ch0);
                ch1 = fmaf(p1.x, wlo, ch1); ch1 = fmaf(p1.y, whi, ch1);
            }
            part_ch[0][c][d] = ch0; part_ch[1][c][d] = ch1;
        }
        __syncthreads();

        // ---- phase 4: output (threads 0-127) + next-pair q preload (128-383) ----
        if (t < 128) {
            const int s = t >> 6, d = t & 63;
            if (s < nS) {
                float sv = 0.f, ch = 0.f;
#pragma unroll
                for (int c = 0; c < 8; c++) { sv += part_sv[s][c][d]; ch += part_ch[s][c][d]; }
                ch = 1.f / (1.f + __expf(-(ch + bc_s[d])));
                const float ov = sv * q2_s[pb][s][d] * ch;
                const int q = q0 + qi + s;
                const int b = bh >> 3, hh = bh & 7;
                attn_v[(((size_t)(b * NQv + q) * NH) + hh) * 64 + d] = ov;
            }
        } else if (t < 384 && qi + 2 < nq) {
            const int tq = t - 128;
            const int s = tq >> 7, rem = tq & 127, kind = rem >> 6, d = rem & 63;
            if (qi + 2 + s < nq) {
                const size_t qb = ((size_t)bh * NQv + q0 + qi + 2 + s) * 64 + d;
                if (kind == 0) q1_s[pb ^ 1][s][d] = q1g[qb]; else q2_s[pb ^ 1][s][d] = q2g[qb];
            }
        }
        __syncthreads();
    }
}

// ---------------- Kernel C: MFMA output projection ----------------
__global__ __launch_bounds__(256) void out_proj_kernel(
    const float* __restrict__ x, const unsigned short* __restrict__ WT,
    const float* __restrict__ bo, float* __restrict__ out)
{
    __shared__ char A_s[64 * 144];
    __shared__ char B_s[64 * 144];

    const int t = threadIdx.x;
    const int r0 = blockIdx.x * 64;
    const int ct = blockIdx.y;

    const int lane = t & 63, wave = t >> 6;
    const int wr = wave >> 1, wc = wave & 1;
    const int lr = lane & 15, lq = lane >> 4;
    const int srow = t >> 2, sc = t & 3;

    f32x4 acc[2][2];
#pragma unroll
    for (int i = 0; i < 2; i++)
#pragma unroll
        for (int j = 0; j < 2; j++) acc[i][j] = (f32x4){0.f, 0.f, 0.f, 0.f};

    const int arow = (r0 + srow < 800) ? (r0 + srow) : 799;

    for (int kk = 0; kk < 8; kk++) {
        const int k0 = kk * 64;
#pragma unroll
        for (int uu = 0; uu < 2; uu++) {
            const int u = sc * 2 + uu;
            float4 f0 = *(const float4*)&x[(size_t)arow * 512 + k0 + u * 8];
            float4 f1 = *(const float4*)&x[(size_t)arow * 512 + k0 + u * 8 + 4];
            uint4 w;
            w.x = pkbf(f0.x, f0.y); w.y = pkbf(f0.z, f0.w);
            w.z = pkbf(f1.x, f1.y); w.w = pkbf(f1.z, f1.w);
            *(uint4*)(A_s + srow * 144 + u * 16) = w;
        }
#pragma unroll
        for (int uu = 0; uu < 2; uu++) {
            const int u = sc * 2 + uu;
            uint4 w = *(const uint4*)((const char*)(WT + (size_t)(ct * 64 + srow) * 512 + k0) + u * 16);
            *(uint4*)(B_s + srow * 144 + u * 16) = w;
        }
        __syncthreads();
#pragma unroll
        for (int ks = 0; ks < 2; ks++) {
            short8 a0 = *(const short8*)(A_s + (wr * 32 + lr) * 144 + (ks * 4 + lq) * 16);
            short8 a1 = *(const short8*)(A_s + (wr * 32 + 16 + lr) * 144 + (ks * 4 + lq) * 16);
            short8 b0 = *(const short8*)(B_s + (wc * 32 + lr) * 144 + (ks * 4 + lq) * 16);
            short8 b1 = *(const short8*)(B_s + (wc * 32 + 16 + lr) * 144 + (ks * 4 + lq) * 16);
            acc[0][0] = __builtin_amdgcn_mfma_f32_16x16x32_bf16(a0, b0, acc[0][0], 0, 0, 0);
            acc[0][1] = __builtin_amdgcn_mfma_f32_16x16x32_bf16(a0, b1, acc[0][1], 0, 0, 0);
            acc[1][0] = __builtin_amdgcn_mfma_f32_16x16x32_bf16(a1, b0, acc[1][0], 0, 0, 0);
            acc[1][1] = __builtin_amdgcn_mfma_f32_16x16x32_bf16(a1, b1, acc[1][1], 0, 0, 0);
        }
        __syncthreads();
    }

#pragma unroll
    for (int nt = 0; nt < 2; nt++) {
        const int j = ct * 64 + wc * 32 + nt * 16 + lr;
        const float bias = bo[j];
#pragma unroll
        for (int mt = 0; mt < 2; mt++) {
#pragma unroll
            for (int r = 0; r < 4; r++) {
                const int rowg = r0 + wr * 32 + mt * 16 + lq * 4 + r;
                if (rowg < 800) out[(size_t)rowg * 512 + j] = acc[mt][nt][r] + bias;
            }
        }
    }
}

extern "C" void kernel_launch(void* const* d_in, const int* in_sizes, int n_in,
                              void* d_out, int out_size, void* d_ws, size_t ws_size,
                              hipStream_t stream) {
    (void)in_sizes; (void)n_in; (void)out_size; (void)ws_size;
    const float* queries = (const float*)d_in[0];
    const float* keys    = (const float*)d_in[1];
    const float* values  = (const float*)d_in[2];
    const float* W_q1 = (const float*)d_in[3];
    const float* b_q1 = (const float*)d_in[4];
    const float* g_q1w = (const float*)d_in[5];
    const float* g_q1b = (const float*)d_in[6];
    const float* W_q2 = (const float*)d_in[7];
    const float* b_q2 = (const float*)d_in[8];
    const float* g_q2w = (const float*)d_in[9];
    const float* g_q2b = (const float*)d_in[10];
    const float* W_k = (const float*)d_in[11];
    const float* b_k = (const float*)d_in[12];
    const float* g_kw = (const float*)d_in[13];
    const float* g_kb = (const float*)d_in[14];
    const float* W_v = (const float*)d_in[15];
    const float* b_v = (const float*)d_in[16];
    const float* g_vw = (const float*)d_in[17];
    const float* g_vb = (const float*)d_in[18];
    const float* W_m = (const float*)d_in[19];
    const float* b_m = (const float*)d_in[20];
    const float* W_s = (const float*)d_in[21];
    const float* b_s = (const float*)d_in[22];
    const float* W_c = (const float*)d_in[23];
    const float* b_c = (const float*)d_in[24];
    const float* W_o = (const float*)d_in[25];
    const float* b_o = (const float*)d_in[26];

    float* ws = (float*)d_ws;
    const size_t PROJ = (size_t)BSv * NQv * 512;  // 409600 floats
    float* q1 = ws;
    float* q2 = q1 + PROJ;
    float* kk = q2 + PROJ;
    float* vv = kk + PROJ;
    float* av = vv + PROJ;   // attn_v [b][q][h][d]
    unsigned short* wt = (unsigned short*)(av + PROJ);  // 5 x [512][512] bf16

    wt_kernel<<<dim3(8, 8, 5), 256, 0, stream>>>(W_q1, W_q2, W_k, W_v, W_o, wt);

    proj_kernel<<<dim3(13, 8, 4), 256, 0, stream>>>(
        queries, keys, values, wt,
        b_q1, g_q1w, g_q1b,
        b_q2, g_q2w, g_q2b,
        b_k, g_kw, g_kb,
        b_v, g_vw, g_vb,
        q1, q2, kk, vv);

    attn_kernel<<<dim3(8, BSv * NH), 512, 0, stream>>>(
        q1, q2, kk, vv, W_m, b_m, W_s, b_s, W_c, b_c, av);

    out_proj_kernel<<<dim3(13, 8), 256, 0, stream>>>(av, wt + (size_t)4 * 512 * 512, b_o, (float*)d_out);
}

// Round 5
// 130.722 us; speedup vs baseline: 1.5580x; 1.5580x over previous
//
#include <hip/hip_runtime.h>
#include <hip/hip_bf16.h>
#include <math.h>

#define NH 8
#define DMv 512
#define BSv 8
#define NQv 100
#define NKv 100

typedef __attribute__((ext_vector_type(8))) short short8;
typedef __attribute__((ext_vector_type(4))) float f32x4;

__device__ __forceinline__ unsigned short bf16u(float f) {
    __hip_bfloat16 h = __float2bfloat16(f);
    return *(unsigned short*)&h;
}
__device__ __forceinline__ float ubf16f(unsigned short u) {
    __hip_bfloat16 h = *(__hip_bfloat16*)&u;
    return __bfloat162float(h);
}
__device__ __forceinline__ unsigned int pkbf(float lo, float hi) {
    return ((unsigned int)bf16u(hi) << 16) | (unsigned int)bf16u(lo);
}

// ---------------- Kernel 0: weight transpose + bf16 convert ----------------
__global__ __launch_bounds__(256) void wt_kernel(
    const float* __restrict__ W_q1, const float* __restrict__ W_q2,
    const float* __restrict__ W_k,  const float* __restrict__ W_v,
    const float* __restrict__ W_o,  unsigned short* __restrict__ wt)
{
    __shared__ float tile[64][68];
    const int z = blockIdx.z;
    const float* W = (z == 0) ? W_q1 : (z == 1) ? W_q2 : (z == 2) ? W_k : (z == 3) ? W_v : W_o;
    unsigned short* out = wt + (size_t)z * 512 * 512;
    const int k0 = blockIdx.x * 64, n0 = blockIdx.y * 64;
    const int t = threadIdx.x;
    const int r = t >> 2, c = t & 3;
#pragma unroll
    for (int i = 0; i < 4; i++) {
        float4 v = *(const float4*)&W[(size_t)(k0 + r) * 512 + n0 + c * 16 + i * 4];
        *(float4*)&tile[r][c * 16 + i * 4] = v;
    }
    __syncthreads();
#pragma unroll
    for (int jj = 0; jj < 4; jj++) {
        const int kb = c * 16 + jj * 4;
        ushort4 u;
        u.x = bf16u(tile[kb + 0][r]); u.y = bf16u(tile[kb + 1][r]);
        u.z = bf16u(tile[kb + 2][r]); u.w = bf16u(tile[kb + 3][r]);
        *(ushort4*)&out[(size_t)(n0 + r) * 512 + k0 + kb] = u;
    }
}

// ---------------- Kernel A: MFMA proj GEMM + bias + ELU + GroupNorm ----------------
__global__ __launch_bounds__(256) void proj_kernel(
    const float* __restrict__ xq, const float* __restrict__ xk, const float* __restrict__ xv,
    const unsigned short* __restrict__ wt,
    const float* __restrict__ bq1, const float* __restrict__ gq1w, const float* __restrict__ gq1b,
    const float* __restrict__ bq2, const float* __restrict__ gq2w, const float* __restrict__ gq2b,
    const float* __restrict__ bk,  const float* __restrict__ gkw,  const float* __restrict__ gkb,
    const float* __restrict__ bv,  const float* __restrict__ gvw,  const float* __restrict__ gvb,
    float* __restrict__ q1o, float* __restrict__ q2o, float* __restrict__ ko, float* __restrict__ vo)
{
    __shared__ char A_s[64 * 144];
    __shared__ char B_s[64 * 144];
    __shared__ float Y_s[64][68];

    const int p = blockIdx.z;
    const float *x, *bb, *gw, *gb;
    float* o;
    if (p == 0)      { x = xq; bb = bq1; gw = gq1w; gb = gq1b; o = q1o; }
    else if (p == 1) { x = xq; bb = bq2; gw = gq2w; gb = gq2b; o = q2o; }
    else if (p == 2) { x = xk; bb = bk;  gw = gkw;  gb = gkb;  o = ko;  }
    else             { x = xv; bb = bv;  gw = gvw;  gb = gvb;  o = vo;  }
    const unsigned short* WT = wt + (size_t)p * 512 * 512;

    const int t = threadIdx.x;
    const int r0 = blockIdx.x * 64;
    const int ct = blockIdx.y;

    const int lane = t & 63, wave = t >> 6;
    const int wr = wave >> 1, wc = wave & 1;
    const int lr = lane & 15, lq = lane >> 4;
    const int srow = t >> 2, sc = t & 3;

    f32x4 acc[2][2];
#pragma unroll
    for (int i = 0; i < 2; i++)
#pragma unroll
        for (int j = 0; j < 2; j++) acc[i][j] = (f32x4){0.f, 0.f, 0.f, 0.f};

    const int arow = (r0 + srow < 800) ? (r0 + srow) : 799;

    for (int kk = 0; kk < 8; kk++) {
        const int k0 = kk * 64;
#pragma unroll
        for (int uu = 0; uu < 2; uu++) {
            const int u = sc * 2 + uu;
            float4 f0 = *(const float4*)&x[(size_t)arow * 512 + k0 + u * 8];
            float4 f1 = *(const float4*)&x[(size_t)arow * 512 + k0 + u * 8 + 4];
            uint4 w;
            w.x = pkbf(f0.x, f0.y); w.y = pkbf(f0.z, f0.w);
            w.z = pkbf(f1.x, f1.y); w.w = pkbf(f1.z, f1.w);
            *(uint4*)(A_s + srow * 144 + u * 16) = w;
        }
#pragma unroll
        for (int uu = 0; uu < 2; uu++) {
            const int u = sc * 2 + uu;
            uint4 w = *(const uint4*)((const char*)(WT + (size_t)(ct * 64 + srow) * 512 + k0) + u * 16);
            *(uint4*)(B_s + srow * 144 + u * 16) = w;
        }
        __syncthreads();
#pragma unroll
        for (int ks = 0; ks < 2; ks++) {
            short8 a0 = *(const short8*)(A_s + (wr * 32 + lr) * 144 + (ks * 4 + lq) * 16);
            short8 a1 = *(const short8*)(A_s + (wr * 32 + 16 + lr) * 144 + (ks * 4 + lq) * 16);
            short8 b0 = *(const short8*)(B_s + (wc * 32 + lr) * 144 + (ks * 4 + lq) * 16);
            short8 b1 = *(const short8*)(B_s + (wc * 32 + 16 + lr) * 144 + (ks * 4 + lq) * 16);
            acc[0][0] = __builtin_amdgcn_mfma_f32_16x16x32_bf16(a0, b0, acc[0][0], 0, 0, 0);
            acc[0][1] = __builtin_amdgcn_mfma_f32_16x16x32_bf16(a0, b1, acc[0][1], 0, 0, 0);
            acc[1][0] = __builtin_amdgcn_mfma_f32_16x16x32_bf16(a1, b0, acc[1][0], 0, 0, 0);
            acc[1][1] = __builtin_amdgcn_mfma_f32_16x16x32_bf16(a1, b1, acc[1][1], 0, 0, 0);
        }
        __syncthreads();
    }

#pragma unroll
    for (int nt = 0; nt < 2; nt++) {
        const int colL = wc * 32 + nt * 16 + lr;
        const float bias = bb[ct * 64 + colL];
#pragma unroll
        for (int mt = 0; mt < 2; mt++) {
#pragma unroll
            for (int r = 0; r < 4; r++) {
                const int row = wr * 32 + mt * 16 + lq * 4 + r;
                float y = acc[mt][nt][r] + bias;
                y = (y > 0.f) ? y : expm1f(y);
                Y_s[row][colL] = y;
            }
        }
    }
    __syncthreads();

    {
        const int row = t >> 2, c = t & 3;
        float v[16];
        float s = 0.f, ss = 0.f;
#pragma unroll
        for (int i = 0; i < 16; i++) {
            v[i] = Y_s[row][c * 16 + i];
            s += v[i]; ss += v[i] * v[i];
        }
        s += __shfl_xor(s, 1); ss += __shfl_xor(ss, 1);
        s += __shfl_xor(s, 2); ss += __shfl_xor(ss, 2);
        const float mu = s * (1.f / 64.f);
        const float var = ss * (1.f / 64.f) - mu * mu;
        const float rs = 1.0f / sqrtf(var + 1e-5f);
        const int rowg = r0 + row;
        if (rowg < 800) {
            const int b = rowg / 100, sq = rowg % 100;
            const size_t base = (((size_t)(b * NH + ct) * NQv) + sq) * 64 + c * 16;
            const int j0 = ct * 64 + c * 16;
#pragma unroll
            for (int i4 = 0; i4 < 4; i4++) {
                float4 gwv = *(const float4*)&gw[j0 + i4 * 4];
                float4 gbv = *(const float4*)&gb[j0 + i4 * 4];
                float4 ov;
                ov.x = (v[i4 * 4 + 0] - mu) * rs * gwv.x + gbv.x;
                ov.y = (v[i4 * 4 + 1] - mu) * rs * gwv.y + gbv.y;
                ov.z = (v[i4 * 4 + 2] - mu) * rs * gwv.z + gbv.z;
                ov.w = (v[i4 * 4 + 3] - mu) * rs * gwv.w + gbv.w;
                *(float4*)&o[base + i4 * 4] = ov;
            }
        }
    }
}

// ---------------- Kernel B v4: 2-q pairing, LDS overlay (Wm/K -> V/Wc), no spills ----------------
// __launch_bounds__ 2nd arg behaves as min BLOCKS/CU on this toolchain (R3 evidence:
// (512,4) -> VGPR capped 64 -> 321MB spill traffic). (512,2): cap 128, need ~110.
__global__ __launch_bounds__(512, 2) void attn_kernel(
    const float* __restrict__ q1g, const float* __restrict__ q2g,
    const float* __restrict__ kg, const float* __restrict__ vg,
    const float* __restrict__ Wm, const float* __restrict__ bm,
    const float* __restrict__ Ws, const float* __restrict__ bs_,
    const float* __restrict__ Wc, const float* __restrict__ bc,
    float* __restrict__ attn_v)
{
    __shared__ union {
        struct { unsigned short Wm[8192]; unsigned short K[8192]; } a;   // prologue: bf16 swizzled
        struct { unsigned int V_pk[3200]; unsigned int Wc_pk[4096]; } b; // q loop: packed pairs
    } ov;
    __shared__ float q1_s[2][2][64];
    __shared__ float q2_s[2][2][64];
    __shared__ float lgp[2][128];
    __shared__ float part_l2[2][2][128];
    __shared__ float part_p3[2][4][132];
    __shared__ float pool_s[2][128];
    __shared__ float part_sv[2][8][64];
    __shared__ float part_ch[2][8][64];
    __shared__ float2 bmws_s[128];
    __shared__ float bc_s[64];

    const int t = threadIdx.x;
    const int qt = blockIdx.x;     // 0..7
    const int bh = blockIdx.y;     // 0..63
    const int q0 = (qt < 4) ? qt * 13 : 52 + (qt - 4) * 12;
    const int nq = (qt < 4) ? 13 : 12;

    const float* Kg = kg + (size_t)bh * NKv * 64;
    const float* Vg = vg + (size_t)bh * NKv * 64;

    // ---- prologue stage 1: Wm, K into LDS (swizzled bf16) ----
    for (int i = t; i < 1024; i += 512) {
        const int k = i >> 3, u = i & 7;
        uint4 w;
        if (k < NKv) {
            float4 a = *(const float4*)(Kg + k * 64 + u * 8);
            float4 b = *(const float4*)(Kg + k * 64 + u * 8 + 4);
            w.x = pkbf(a.x, a.y); w.y = pkbf(a.z, a.w);
            w.z = pkbf(b.x, b.y); w.w = pkbf(b.z, b.w);
        } else { w.x = 0u; w.y = 0u; w.z = 0u; w.w = 0u; }
        *(uint4*)((char*)ov.a.K + k * 128 + ((u ^ (k & 7)) * 16)) = w;
    }
    for (int i = t; i < 1024; i += 512) {
        const int u = i >> 7, m = i & 127;
        float f[8];
#pragma unroll
        for (int j = 0; j < 8; j++) f[j] = Wm[(size_t)(u * 8 + j) * 128 + m];
        uint4 w;
        w.x = pkbf(f[0], f[1]); w.y = pkbf(f[2], f[3]);
        w.z = pkbf(f[4], f[5]); w.w = pkbf(f[6], f[7]);
        *(uint4*)((char*)ov.a.Wm + m * 128 + ((u ^ (m & 7)) * 16)) = w;
    }
    if (t < 128) bmws_s[t] = make_float2(bm[t], Ws[t]);
    if (t < 64) bc_s[t] = bc[t];
    if (t >= 128 && t < 384) {
        const int tq = t - 128;
        const int s = tq >> 7, rem = tq & 127, kind = rem >> 6, d = rem & 63;
        const size_t qb = ((size_t)bh * NQv + q0 + s) * 64 + d;
        if (kind == 0) q1_s[0][s][d] = q1g[qb]; else q2_s[0][s][d] = q2g[qb];
    }
    const float bsv = bs_[0];
    __syncthreads();

    // ---- prologue stage 2: hoist fragments to registers ----
    const int lane = t & 63, wave = t >> 6;
    const int mrow = wave >> 2, ncol = wave & 3;
    const int lr = lane & 15, lq = lane >> 4;

    short8 afr[4][2];
#pragma unroll
    for (int mti = 0; mti < 4; mti++)
#pragma unroll
        for (int ks = 0; ks < 2; ks++) {
            const int m = mrow * 64 + mti * 16 + lr;
            const int u = ks * 4 + lq;
            afr[mti][ks] = *(const short8*)((const char*)ov.a.Wm + m * 128 + ((u ^ (m & 7)) * 16));
        }
    uint4 Ku[2][2];
#pragma unroll
    for (int nti = 0; nti < 2; nti++)
#pragma unroll
        for (int ks = 0; ks < 2; ks++) {
            const int k = ncol * 32 + nti * 16 + lr;
            const int u = ks * 4 + lq;
            Ku[nti][ks] = *(const uint4*)((const char*)ov.a.K + k * 128 + ((u ^ (k & 7)) * 16));
        }
    const float km0 = (ncol * 32 + lr < 100) ? 1.f : 0.f;
    const float km1 = (ncol * 32 + 16 + lr < 100) ? 1.f : 0.f;
    __syncthreads();

    // ---- prologue stage 3: overlay V_pk / Wc_pk into the same LDS ----
    for (int i = t; i < 800; i += 512) {
        const int k2 = i >> 4, du = i & 15;
        float4 a = *(const float4*)(Vg + (size_t)(2 * k2) * 64 + du * 4);
        float4 b = *(const float4*)(Vg + (size_t)(2 * k2 + 1) * 64 + du * 4);
        uint4 w;
        w.x = pkbf(a.x, b.x); w.y = pkbf(a.y, b.y);
        w.z = pkbf(a.z, b.z); w.w = pkbf(a.w, b.w);
        *(uint4*)(ov.b.V_pk + k2 * 64 + du * 4) = w;
    }
    for (int i = t; i < 1024; i += 512) {
        const int m2 = i >> 4, du = i & 15;
        float4 a = *(const float4*)(Wc + (size_t)(2 * m2) * 64 + du * 4);
        float4 b = *(const float4*)(Wc + (size_t)(2 * m2 + 1) * 64 + du * 4);
        uint4 w;
        w.x = pkbf(a.x, b.x); w.y = pkbf(a.y, b.y);
        w.z = pkbf(a.z, b.z); w.w = pkbf(a.w, b.w);
        *(uint4*)(ov.b.Wc_pk + m2 * 64 + du * 4) = w;
    }
    __syncthreads();

    for (int qi = 0; qi < nq; qi += 2) {
        const int pb = (qi >> 1) & 1;
        const bool has2 = (qi + 1 < nq);
        const int nS = has2 ? 2 : 1;

        // ---- phase 1: MFMA S + fused logits/pool partials ----
        for (int s = 0; s < nS; s++) {
            f32x4 acc[4][2];
#pragma unroll
            for (int mti = 0; mti < 4; mti++)
#pragma unroll
                for (int nti = 0; nti < 2; nti++) acc[mti][nti] = (f32x4){0.f, 0.f, 0.f, 0.f};

#pragma unroll
            for (int ks = 0; ks < 2; ks++) {
                float q1v[8];
                {
                    float4 x = *(const float4*)((const char*)q1_s[pb][s] + ks * 128 + lq * 32);
                    float4 y = *(const float4*)((const char*)q1_s[pb][s] + ks * 128 + lq * 32 + 16);
                    q1v[0] = x.x; q1v[1] = x.y; q1v[2] = x.z; q1v[3] = x.w;
                    q1v[4] = y.x; q1v[5] = y.y; q1v[6] = y.z; q1v[7] = y.w;
                }
                union { short8 s8; unsigned int u[4]; } bfr0, bfr1;
#pragma unroll
                for (int w = 0; w < 4; w++) {
                    const unsigned int u0 = ((const unsigned int*)&Ku[0][ks])[w];
                    const unsigned int u1 = ((const unsigned int*)&Ku[1][ks])[w];
                    const float k0lo = __uint_as_float(u0 << 16);
                    const float k0hi = __uint_as_float(u0 & 0xffff0000u);
                    const float k1lo = __uint_as_float(u1 << 16);
                    const float k1hi = __uint_as_float(u1 & 0xffff0000u);
                    bfr0.u[w] = pkbf(k0lo * q1v[2 * w], k0hi * q1v[2 * w + 1]);
                    bfr1.u[w] = pkbf(k1lo * q1v[2 * w], k1hi * q1v[2 * w + 1]);
                }
#pragma unroll
                for (int mti = 0; mti < 4; mti++) {
                    acc[mti][0] = __builtin_amdgcn_mfma_f32_16x16x32_bf16(afr[mti][ks], bfr0.s8, acc[mti][0], 0, 0, 0);
                    acc[mti][1] = __builtin_amdgcn_mfma_f32_16x16x32_bf16(afr[mti][ks], bfr1.s8, acc[mti][1], 0, 0, 0);
                }
            }

            float lp0 = 0.f, lp1 = 0.f;
#pragma unroll
            for (int mti = 0; mti < 4; mti++) {
                float ppv[4];
#pragma unroll
                for (int r = 0; r < 4; r++) {
                    const int m = mrow * 64 + mti * 16 + lq * 4 + r;
                    const float2 bw = bmws_s[m];
                    const float v0 = fmaxf(acc[mti][0][r] + bw.x, 0.f);
                    const float v1 = fmaxf(acc[mti][1][r] + bw.x, 0.f);
                    lp0 = fmaf(bw.y, v0, lp0);
                    lp1 = fmaf(bw.y, v1, lp1);
                    float pv = v0 * km0 + v1 * km1;
                    pv += __shfl_xor(pv, 1);
                    pv += __shfl_xor(pv, 2);
                    pv += __shfl_xor(pv, 4);
                    pv += __shfl_xor(pv, 8);
                    ppv[r] = pv;
                }
                if (lr == 0)
                    *(float4*)&part_p3[s][ncol][mrow * 64 + mti * 16 + lq * 4] =
                        make_float4(ppv[0], ppv[1], ppv[2], ppv[3]);
            }
            lp0 += __shfl_xor(lp0, 16); lp0 += __shfl_xor(lp0, 32);
            lp1 += __shfl_xor(lp1, 16); lp1 += __shfl_xor(lp1, 32);
            if (lane < 16) part_l2[s][mrow][ncol * 32 + lane] = lp0;
            else if (lane < 32) part_l2[s][mrow][ncol * 32 + lane] = lp1;
        }
        __syncthreads();

        // ---- phase 2: softmax + pool finalize ----
        if (t < 128) {
            const int s = t >> 6, l = t & 63;
            if (s < nS) {
                float x0 = part_l2[s][0][l] + part_l2[s][1][l] + bsv;
                float x1 = (l < 36) ? (part_l2[s][0][64 + l] + part_l2[s][1][64 + l] + bsv) : -3.0e38f;
                float mx = fmaxf(x0, x1);
#pragma unroll
                for (int msk = 1; msk <= 32; msk <<= 1) mx = fmaxf(mx, __shfl_xor(mx, msk));
                const float e0 = __expf(x0 - mx);
                const float e1 = (l < 36) ? __expf(x1 - mx) : 0.f;
                float sm = e0 + e1;
#pragma unroll
                for (int msk = 1; msk <= 32; msk <<= 1) sm += __shfl_xor(sm, msk);
                const float inv = 1.f / sm;
                lgp[s][l] = e0 * inv;
                lgp[s][64 + l] = (l < 36) ? e1 * inv : 0.f;
            }
        } else if (t < 384) {
            const int s = (t - 128) >> 7, mm = (t - 128) & 127;
            if (s < nS)
                pool_s[s][mm] = (part_p3[s][0][mm] + part_p3[s][1][mm] +
                                 part_p3[s][2][mm] + part_p3[s][3][mm]) * 0.01f;
        }
        __syncthreads();

        // ---- phase 3: sv / ch partials (both q) ----
        {
            const int d = t & 63, c = t >> 6;
            float sv0 = 0.f, sv1 = 0.f;
            const int k20 = c * 7;
            const int k21 = (k20 + 7 < 50) ? (k20 + 7) : 50;
            for (int k2 = k20; k2 < k21; k2++) {
                const unsigned int vp = ov.b.V_pk[k2 * 64 + d];
                const float vlo = __uint_as_float(vp << 16);
                const float vhi = __uint_as_float(vp & 0xffff0000u);
                const float2 l0 = *(const float2*)&lgp[0][2 * k2];
                const float2 l1 = *(const float2*)&lgp[1][2 * k2];
                sv0 = fmaf(l0.x, vlo, sv0); sv0 = fmaf(l0.y, vhi, sv0);
                sv1 = fmaf(l1.x, vlo, sv1); sv1 = fmaf(l1.y, vhi, sv1);
            }
            part_sv[0][c][d] = sv0; part_sv[1][c][d] = sv1;
            float ch0 = 0.f, ch1 = 0.f;
#pragma unroll
            for (int i = 0; i < 8; i++) {
                const int m2 = c * 8 + i;
                const unsigned int wp = ov.b.Wc_pk[m2 * 64 + d];
                const float wlo = __uint_as_float(wp << 16);
                const float whi = __uint_as_float(wp & 0xffff0000u);
                const float2 p0 = *(const float2*)&pool_s[0][2 * m2];
                const float2 p1 = *(const float2*)&pool_s[1][2 * m2];
                ch0 = fmaf(p0.x, wlo, ch0); ch0 = fmaf(p0.y, whi, ch0);
                ch1 = fmaf(p1.x, wlo, ch1); ch1 = fmaf(p1.y, whi, ch1);
            }
            part_ch[0][c][d] = ch0; part_ch[1][c][d] = ch1;
        }
        __syncthreads();

        // ---- phase 4: output + next-pair q preload ----
        if (t < 128) {
            const int s = t >> 6, d = t & 63;
            if (s < nS) {
                float sv = 0.f, ch = 0.f;
#pragma unroll
                for (int c = 0; c < 8; c++) { sv += part_sv[s][c][d]; ch += part_ch[s][c][d]; }
                ch = 1.f / (1.f + __expf(-(ch + bc_s[d])));
                const float ov_ = sv * q2_s[pb][s][d] * ch;
                const int q = q0 + qi + s;
                const int b = bh >> 3, hh = bh & 7;
                attn_v[(((size_t)(b * NQv + q) * NH) + hh) * 64 + d] = ov_;
            }
        } else if (t < 384 && qi + 2 < nq) {
            const int tq = t - 128;
            const int s = tq >> 7, rem = tq & 127, kind = rem >> 6, d = rem & 63;
            if (qi + 2 + s < nq) {
                const size_t qb = ((size_t)bh * NQv + q0 + qi + 2 + s) * 64 + d;
                if (kind == 0) q1_s[pb ^ 1][s][d] = q1g[qb]; else q2_s[pb ^ 1][s][d] = q2g[qb];
            }
        }
        __syncthreads();
    }
}

// ---------------- Kernel C: MFMA output projection ----------------
__global__ __launch_bounds__(256) void out_proj_kernel(
    const float* __restrict__ x, const unsigned short* __restrict__ WT,
    const float* __restrict__ bo, float* __restrict__ out)
{
    __shared__ char A_s[64 * 144];
    __shared__ char B_s[64 * 144];

    const int t = threadIdx.x;
    const int r0 = blockIdx.x * 64;
    const int ct = blockIdx.y;

    const int lane = t & 63, wave = t >> 6;
    const int wr = wave >> 1, wc = wave & 1;
    const int lr = lane & 15, lq = lane >> 4;
    const int srow = t >> 2, sc = t & 3;

    f32x4 acc[2][2];
#pragma unroll
    for (int i = 0; i < 2; i++)
#pragma unroll
        for (int j = 0; j < 2; j++) acc[i][j] = (f32x4){0.f, 0.f, 0.f, 0.f};

    const int arow = (r0 + srow < 800) ? (r0 + srow) : 799;

    for (int kk = 0; kk < 8; kk++) {
        const int k0 = kk * 64;
#pragma unroll
        for (int uu = 0; uu < 2; uu++) {
            const int u = sc * 2 + uu;
            float4 f0 = *(const float4*)&x[(size_t)arow * 512 + k0 + u * 8];
            float4 f1 = *(const float4*)&x[(size_t)arow * 512 + k0 + u * 8 + 4];
            uint4 w;
            w.x = pkbf(f0.x, f0.y); w.y = pkbf(f0.z, f0.w);
            w.z = pkbf(f1.x, f1.y); w.w = pkbf(f1.z, f1.w);
            *(uint4*)(A_s + srow * 144 + u * 16) = w;
        }
#pragma unroll
        for (int uu = 0; uu < 2; uu++) {
            const int u = sc * 2 + uu;
            uint4 w = *(const uint4*)((const char*)(WT + (size_t)(ct * 64 + srow) * 512 + k0) + u * 16);
            *(uint4*)(B_s + srow * 144 + u * 16) = w;
        }
        __syncthreads();
#pragma unroll
        for (int ks = 0; ks < 2; ks++) {
            short8 a0 = *(const short8*)(A_s + (wr * 32 + lr) * 144 + (ks * 4 + lq) * 16);
            short8 a1 = *(const short8*)(A_s + (wr * 32 + 16 + lr) * 144 + (ks * 4 + lq) * 16);
            short8 b0 = *(const short8*)(B_s + (wc * 32 + lr) * 144 + (ks * 4 + lq) * 16);
            short8 b1 = *(const short8*)(B_s + (wc * 32 + 16 + lr) * 144 + (ks * 4 + lq) * 16);
            acc[0][0] = __builtin_amdgcn_mfma_f32_16x16x32_bf16(a0, b0, acc[0][0], 0, 0, 0);
            acc[0][1] = __builtin_amdgcn_mfma_f32_16x16x32_bf16(a0, b1, acc[0][1], 0, 0, 0);
            acc[1][0] = __builtin_amdgcn_mfma_f32_16x16x32_bf16(a1, b0, acc[1][0], 0, 0, 0);
            acc[1][1] = __builtin_amdgcn_mfma_f32_16x16x32_bf16(a1, b1, acc[1][1], 0, 0, 0);
        }
        __syncthreads();
    }

#pragma unroll
    for (int nt = 0; nt < 2; nt++) {
        const int j = ct * 64 + wc * 32 + nt * 16 + lr;
        const float bias = bo[j];
#pragma unroll
        for (int mt = 0; mt < 2; mt++) {
#pragma unroll
            for (int r = 0; r < 4; r++) {
                const int rowg = r0 + wr * 32 + mt * 16 + lq * 4 + r;
                if (rowg < 800) out[(size_t)rowg * 512 + j] = acc[mt][nt][r] + bias;
            }
        }
    }
}

extern "C" void kernel_launch(void* const* d_in, const int* in_sizes, int n_in,
                              void* d_out, int out_size, void* d_ws, size_t ws_size,
                              hipStream_t stream) {
    (void)in_sizes; (void)n_in; (void)out_size; (void)ws_size;
    const float* queries = (const float*)d_in[0];
    const float* keys    = (const float*)d_in[1];
    const float* values  = (const float*)d_in[2];
    const float* W_q1 = (const float*)d_in[3];
    const float* b_q1 = (const float*)d_in[4];
    const float* g_q1w = (const float*)d_in[5];
    const float* g_q1b = (const float*)d_in[6];
    const float* W_q2 = (const float*)d_in[7];
    const float* b_q2 = (const float*)d_in[8];
    const float* g_q2w = (const float*)d_in[9];
    const float* g_q2b = (const float*)d_in[10];
    const float* W_k = (const float*)d_in[11];
    const float* b_k = (const float*)d_in[12];
    const float* g_kw = (const float*)d_in[13];
    const float* g_kb = (const float*)d_in[14];
    const float* W_v = (const float*)d_in[15];
    const float* b_v = (const float*)d_in[16];
    const float* g_vw = (const float*)d_in[17];
    const float* g_vb = (const float*)d_in[18];
    const float* W_m = (const float*)d_in[19];
    const float* b_m = (const float*)d_in[20];
    const float* W_s = (const float*)d_in[21];
    const float* b_s = (const float*)d_in[22];
    const float* W_c = (const float*)d_in[23];
    const float* b_c = (const float*)d_in[24];
    const float* W_o = (const float*)d_in[25];
    const float* b_o = (const float*)d_in[26];

    float* ws = (float*)d_ws;
    const size_t PROJ = (size_t)BSv * NQv * 512;  // 409600 floats
    float* q1 = ws;
    float* q2 = q1 + PROJ;
    float* kk = q2 + PROJ;
    float* vv = kk + PROJ;
    float* av = vv + PROJ;   // attn_v [b][q][h][d]
    unsigned short* wt = (unsigned short*)(av + PROJ);  // 5 x [512][512] bf16

    wt_kernel<<<dim3(8, 8, 5), 256, 0, stream>>>(W_q1, W_q2, W_k, W_v, W_o, wt);

    proj_kernel<<<dim3(13, 8, 4), 256, 0, stream>>>(
        queries, keys, values, wt,
        b_q1, g_q1w, g_q1b,
        b_q2, g_q2w, g_q2b,
        b_k, g_kw, g_kb,
        b_v, g_vw, g_vb,
        q1, q2, kk, vv);

    attn_kernel<<<dim3(8, BSv * NH), 512, 0, stream>>>(
        q1, q2, kk, vv, W_m, b_m, W_s, b_s, W_c, b_c, av);

    out_proj_kernel<<<dim3(13, 8), 256, 0, stream>>>(av, wt + (size_t)4 * 512 * 512, b_o, (float*)d_out);
}